// Round 10
// baseline (71.705 us; speedup 1.0000x reference)
//
#include <hip/hip_runtime.h>
#include <math.h>
#include <stdint.h>

// Router: scores = x @ emb^T [32768 x 64] fp32-accurate, top-2 + 2-way softmax.
//
// Error-free split-bf16 MFMA (round 9, passed): 3 bf16 limbs per fp32 operand,
// 6 limb-product MFMA passes accumulated in fp32 (error ~3e-7 < fp32-VALU ref).
// Round-9 was latency-bound (MfmaUtil 11 / VALU 14 / HBM 11): B-frag lookahead
// was one TILE (~35 cyc cover vs ~200 cyc L2), x lookahead 2 bodies vs ~900 cyc
// HBM. This round: B prefetch at kk-granularity into ping-pong register pair
// (BA/BB, cover = full body ~300 cyc), x prefetch 4-deep via parity-4 named
// buffers (cover ~3 bodies ~900 cyc). Everything statically indexed via
// unroll-4 macro bodies -- no dynamic-index scratch, no spill (watch WRITE).
//
// Wave = 16 tokens x 64 experts (4 N-tiles of mfma_f32_16x16x32_bf16).
// C-layout (m89): col=lane&15, row=(lane>>4)*4+reg. Top-2 via 4-step shfl_xor
// merge over the 16-lane group, lowest-index tie-break. emb limbs prepacked in
// ws as ready B-frags (384 KB, L2-resident).

typedef __attribute__((ext_vector_type(8))) short short8;
typedef __attribute__((ext_vector_type(4))) float f32x4;

constexpr int HDIM = 1024;
constexpr int NEXP = 64;
constexpr int TPB  = 64;            // tokens per block (4 waves x 16)
constexpr int NTHREADS = 256;
constexpr int NKK  = 32;            // K-steps of 32

__device__ __forceinline__ uint32_t cvtpk_bf16(float lo, float hi) {
    uint32_t r;
    asm("v_cvt_pk_bf16_f32 %0, %1, %2" : "=v"(r) : "v"(lo), "v"(hi));
    return r;
}

// RNE 3-limb bf16 split of 8 fp32 values; outputs packed frag words.
__device__ __forceinline__ void split8(const float4& A, const float4& B,
                                       uint32_t w0[4], uint32_t w1[4],
                                       uint32_t w2[4])
{
    const float p[8] = {A.x, A.y, A.z, A.w, B.x, B.y, B.z, B.w};
#pragma unroll
    for (int m = 0; m < 4; ++m) {
        const float lo = p[2 * m], hi = p[2 * m + 1];
        const uint32_t c0 = cvtpk_bf16(lo, hi);
        const float l0 = __uint_as_float(c0 << 16);
        const float h0 = __uint_as_float(c0 & 0xFFFF0000u);
        const float rl = lo - l0, rh = hi - h0;         // exact
        const uint32_t c1 = cvtpk_bf16(rl, rh);
        const float l1 = __uint_as_float(c1 << 16);
        const float h1 = __uint_as_float(c1 & 0xFFFF0000u);
        const uint32_t c2 = cvtpk_bf16(rl - l1, rh - h1);
        w0[m] = c0; w1[m] = c1; w2[m] = c2;
    }
}

__device__ __forceinline__ short8 frag_of(uint32_t a, uint32_t b,
                                          uint32_t c, uint32_t d) {
    union { uint4 u; short8 s; } cv;
    cv.u = make_uint4(a, b, c, d);
    return cv.s;
}
__device__ __forceinline__ short8 frag_of4(const uint4& v) {
    union { uint4 u; short8 s; } cv;
    cv.u = v;
    return cv.s;
}

// prepack: B-frags for mfma. wsb[f] with f=[kk][t][lane]: lane l holds
// emb[t*16+(l&15)][kk*32+(l>>4)*8 .. +7] as bf16x8; three limb arrays.
__global__ __launch_bounds__(256)
void prepack_kernel(const float* __restrict__ emb, uint4* __restrict__ wsb)
{
    const int f  = blockIdx.x * 256 + threadIdx.x;   // 0..8191
    const int l  = f & 63, t = (f >> 6) & 3, kk = f >> 8;
    const int e  = t * 16 + (l & 15);
    const int k0 = kk * 32 + (l >> 4) * 8;
    const float4 A = *(const float4*)(emb + (size_t)e * HDIM + k0);
    const float4 B = *(const float4*)(emb + (size_t)e * HDIM + k0 + 4);
    uint32_t w0[4], w1[4], w2[4];
    split8(A, B, w0, w1, w2);
    wsb[f]         = make_uint4(w0[0], w0[1], w0[2], w0[3]);
    wsb[f + 8192]  = make_uint4(w1[0], w1[1], w1[2], w1[3]);
    wsb[f + 16384] = make_uint4(w2[0], w2[1], w2[2], w2[3]);
}

__global__ __launch_bounds__(NTHREADS, 2)
void router_kernel(const float* __restrict__ x,
                   const uint4* __restrict__ wsb,
                   float* __restrict__ out)
{
    __shared__ float4 cand2[TPB];    // (p1,p2,E1,E2) per token

    const int tid  = threadIdx.x;
    const int lane = tid & 63;
    const int w    = tid >> 6;
    const int tok0 = blockIdx.x * TPB;
    const int col  = lane & 15;      // token row (A) / expert col (C)
    const int grp  = lane >> 4;

    // A-operand source: lane holds token (w*16+col), k-slice grp*8..+7 per kk
    const float* xrow = x + (size_t)(tok0 + w * 16 + col) * HDIM + grp * 8;

    f32x4 acc[4] = {{0,0,0,0}, {0,0,0,0}, {0,0,0,0}, {0,0,0,0}};

    // ---- x prefetch, 4 deep (parity-4 named buffers) ----
    float4 x00 = *(const float4*)(xrow +  0), x01 = *(const float4*)(xrow +  4);
    float4 x10 = *(const float4*)(xrow + 32), x11 = *(const float4*)(xrow + 36);
    float4 x20 = *(const float4*)(xrow + 64), x21 = *(const float4*)(xrow + 68);
    float4 x30 = *(const float4*)(xrow + 96), x31 = *(const float4*)(xrow + 100);

    // ---- B ping-pong buffers: whole-kk granularity (4 tiles x 3 limbs) ----
    uint4 BA[4][3], BB[4][3];

#define LOADB(BUF, KKN)                                                        \
    do {                                                                       \
        const int base_ = (KKN) * 256 + lane;                                  \
        _Pragma("unroll")                                                      \
        for (int t_ = 0; t_ < 4; ++t_) {                                       \
            BUF[t_][0] = wsb[base_ + t_ * 64];                                 \
            BUF[t_][1] = wsb[8192 + base_ + t_ * 64];                          \
            BUF[t_][2] = wsb[16384 + base_ + t_ * 64];                         \
        }                                                                      \
    } while (0)

    LOADB(BA, 0);

    // One kk body: prefetch B(kk+1) into BN, split x(kk), prefetch x(kk+4),
    // 24 MFMAs on BC. LB/LX are literal flags (compile-time folded).
#define BODY(KK, BC, BN, XA, XB, LB, LX)                                       \
    do {                                                                       \
        if (LB) LOADB(BN, (KK) + 1);                                           \
        uint32_t w0_[4], w1_[4], w2_[4];                                       \
        split8(XA, XB, w0_, w1_, w2_);                                         \
        const short8 fa0 = frag_of(w0_[0], w0_[1], w0_[2], w0_[3]);            \
        const short8 fa1 = frag_of(w1_[0], w1_[1], w1_[2], w1_[3]);            \
        const short8 fa2 = frag_of(w2_[0], w2_[1], w2_[2], w2_[3]);            \
        if (LX) {                                                              \
            XA = *(const float4*)(xrow + ((KK) + 4) * 32);                     \
            XB = *(const float4*)(xrow + ((KK) + 4) * 32 + 4);                 \
        }                                                                      \
        _Pragma("unroll")                                                      \
        for (int t_ = 0; t_ < 4; ++t_) {                                       \
            const short8 fb0 = frag_of4(BC[t_][0]);                            \
            const short8 fb1 = frag_of4(BC[t_][1]);                            \
            const short8 fb2 = frag_of4(BC[t_][2]);                            \
            f32x4 a_ = acc[t_];                                                \
            a_ = __builtin_amdgcn_mfma_f32_16x16x32_bf16(fa2, fb0, a_, 0,0,0); \
            a_ = __builtin_amdgcn_mfma_f32_16x16x32_bf16(fa0, fb2, a_, 0,0,0); \
            a_ = __builtin_amdgcn_mfma_f32_16x16x32_bf16(fa1, fb1, a_, 0,0,0); \
            a_ = __builtin_amdgcn_mfma_f32_16x16x32_bf16(fa1, fb0, a_, 0,0,0); \
            a_ = __builtin_amdgcn_mfma_f32_16x16x32_bf16(fa0, fb1, a_, 0,0,0); \
            a_ = __builtin_amdgcn_mfma_f32_16x16x32_bf16(fa0, fb0, a_, 0,0,0); \
            acc[t_] = a_;                                                      \
        }                                                                      \
    } while (0)

#pragma unroll 1
    for (int kk4 = 0; kk4 < NKK - 4; kk4 += 4) {
        BODY(kk4 + 0, BA, BB, x00, x01, 1, 1);
        BODY(kk4 + 1, BB, BA, x10, x11, 1, 1);
        BODY(kk4 + 2, BA, BB, x20, x21, 1, 1);
        BODY(kk4 + 3, BB, BA, x30, x31, 1, 1);
    }
    // tail kk = 28..31 (no x prefetch; last body no B prefetch)
    BODY(28, BA, BB, x00, x01, 1, 0);
    BODY(29, BB, BA, x10, x11, 1, 0);
    BODY(30, BA, BB, x20, x21, 1, 0);
    BODY(31, BB, BA, x30, x31, 0, 0);
#undef BODY
#undef LOADB

    // ---- top-2 epilogue. Lane holds tokens r=grp*4+i (i=reg) for experts
    // t*16+col. Merge across the 16-lane group (masks 1,2,4,8), lowest
    // expert index wins exact ties.
#define INS(v, e)                                                              \
    do {                                                                       \
        const float _v = (v); const int _e = (e);                              \
        if (_v > V1 || (_v == V1 && _e < E1)) {                                \
            V2 = V1; E2 = E1; V1 = _v; E1 = _e;                                \
        } else if (_v > V2 || (_v == V2 && _e < E2)) {                         \
            V2 = _v; E2 = _e;                                                  \
        }                                                                      \
    } while (0)

#pragma unroll
    for (int i = 0; i < 4; ++i) {
        float V1 = acc[0][i]; int E1 = col;
        float V2 = -INFINITY; int E2 = NEXP;
        INS(acc[1][i], 16 + col);
        INS(acc[2][i], 32 + col);
        INS(acc[3][i], 48 + col);
#pragma unroll
        for (int m = 1; m <= 8; m <<= 1) {
            const float pv1 = __shfl_xor(V1, m, 64);
            const int   pe1 = __shfl_xor(E1, m, 64);
            const float pv2 = __shfl_xor(V2, m, 64);
            const int   pe2 = __shfl_xor(E2, m, 64);
            INS(pv1, pe1);
            INS(pv2, pe2);
        }
        if (col == 0) {
            const float et = expf(V2 - V1);
            float4 c;
            c.x = 1.f / (1.f + et);
            c.y = et / (1.f + et);
            c.z = __int_as_float(E1);
            c.w = __int_as_float(E2);
            cand2[w * 16 + grp * 4 + i] = c;
        }
    }
#undef INS
    __syncthreads();

    // ---- coalesced output: 64 tokens x 16 quads = 1024 float4 ----
#pragma unroll
    for (int jj = 0; jj < 4; ++jj) {
        const int G = jj * NTHREADS + tid;     // 0..1023
        const int tt = G >> 4, q = G & 15;
        const float4 c = cand2[tt];
        const int E1 = __float_as_int(c.z), E2 = __float_as_int(c.w);
        float4 o;
        float* of = (float*)&o;
#pragma unroll
        for (int ii = 0; ii < 4; ++ii) {
            const int e = 4 * q + ii;
            of[ii] = (e == E1) ? c.x : (e == E2) ? c.y : 0.f;
        }
        *(float4*)(out + (size_t)(tok0 + tt) * NEXP + q * 4) = o;
    }
}

extern "C" void kernel_launch(void* const* d_in, const int* in_sizes, int n_in,
                              void* d_out, int out_size, void* d_ws, size_t ws_size,
                              hipStream_t stream)
{
    const float* x   = (const float*)d_in[0];
    const float* emb = (const float*)d_in[1];
    float* out = (float*)d_out;
    uint4* wsb = (uint4*)d_ws;                   // 384 KiB: 3 limb B-frag arrays

    prepack_kernel<<<32, 256, 0, stream>>>(emb, wsb);

    const int n_tokens = in_sizes[0] / HDIM;     // 32768
    const int nblocks  = n_tokens / TPB;         // 512

    router_kernel<<<nblocks, NTHREADS, 0, stream>>>(x, wsb, out);
}

// Round 11
// 57.604 us; speedup vs baseline: 1.2448x; 1.2448x over previous
//
#include <hip/hip_runtime.h>
#include <math.h>
#include <stdint.h>

// Router: scores = x @ emb^T [32768 x 64] fp32-accurate, top-2 + 2-way softmax.
//
// Error-free split-bf16 MFMA (rounds 9/10, passes): 3 bf16 limbs per fp32
// operand, 6 limb-product MFMA passes accumulated in fp32 (~3e-7 error).
// Rounds 9/10 were LATENCY-bound at 2 waves/SIMD (grid-capped); round 10
// proved the compiler defeats register-level prefetch (sank my 96-reg
// ping-pong back to short lookahead). This round hides latency with TLP
// instead: SPLIT-K x4 -- block = 4 waves = one 16-token tile, wave w owns
// K quarter [256w, 256w+256). Grid 2048 blocks = 8 blocks/CU = 8 waves/SIMD
// (4x). __launch_bounds__(256,8) caps VGPR at 64 (round 9 used 44).
// Epilogue: LDS partial reduce (fixed order, deterministic), 16-lane shfl
// top-2, 4-group merge, coalesced float4 store.

typedef __attribute__((ext_vector_type(8))) short short8;
typedef __attribute__((ext_vector_type(4))) float f32x4;

constexpr int HDIM = 1024;
constexpr int NEXP = 64;
constexpr int TPB  = 16;            // tokens per block (one M-tile)
constexpr int NTHREADS = 256;
constexpr int NKKW = 8;             // kk steps of 32 per wave (K quarter)

__device__ __forceinline__ uint32_t cvtpk_bf16(float lo, float hi) {
    uint32_t r;
    asm("v_cvt_pk_bf16_f32 %0, %1, %2" : "=v"(r) : "v"(lo), "v"(hi));
    return r;
}

// RNE 3-limb bf16 split of 8 fp32 values; outputs packed frag words.
__device__ __forceinline__ void split8(const float4& A, const float4& B,
                                       uint32_t w0[4], uint32_t w1[4],
                                       uint32_t w2[4])
{
    const float p[8] = {A.x, A.y, A.z, A.w, B.x, B.y, B.z, B.w};
#pragma unroll
    for (int m = 0; m < 4; ++m) {
        const float lo = p[2 * m], hi = p[2 * m + 1];
        const uint32_t c0 = cvtpk_bf16(lo, hi);
        const float l0 = __uint_as_float(c0 << 16);
        const float h0 = __uint_as_float(c0 & 0xFFFF0000u);
        const float rl = lo - l0, rh = hi - h0;         // exact
        const uint32_t c1 = cvtpk_bf16(rl, rh);
        const float l1 = __uint_as_float(c1 << 16);
        const float h1 = __uint_as_float(c1 & 0xFFFF0000u);
        const uint32_t c2 = cvtpk_bf16(rl - l1, rh - h1);
        w0[m] = c0; w1[m] = c1; w2[m] = c2;
    }
}

__device__ __forceinline__ short8 frag_of(uint32_t a, uint32_t b,
                                          uint32_t c, uint32_t d) {
    union { uint4 u; short8 s; } cv;
    cv.u = make_uint4(a, b, c, d);
    return cv.s;
}
__device__ __forceinline__ short8 frag_of4(const uint4& v) {
    union { uint4 u; short8 s; } cv;
    cv.u = v;
    return cv.s;
}

// prepack: B-frags for mfma. wsb[f] with f=[kk][t][lane]: lane l holds
// emb[t*16+(l&15)][kk*32+(l>>4)*8 .. +7] as bf16x8; three limb arrays.
__global__ __launch_bounds__(256)
void prepack_kernel(const float* __restrict__ emb, uint4* __restrict__ wsb)
{
    const int f  = blockIdx.x * 256 + threadIdx.x;   // 0..8191
    const int l  = f & 63, t = (f >> 6) & 3, kk = f >> 8;
    const int e  = t * 16 + (l & 15);
    const int k0 = kk * 32 + (l >> 4) * 8;
    const float4 A = *(const float4*)(emb + (size_t)e * HDIM + k0);
    const float4 B = *(const float4*)(emb + (size_t)e * HDIM + k0 + 4);
    uint32_t w0[4], w1[4], w2[4];
    split8(A, B, w0, w1, w2);
    wsb[f]         = make_uint4(w0[0], w0[1], w0[2], w0[3]);
    wsb[f + 8192]  = make_uint4(w1[0], w1[1], w1[2], w1[3]);
    wsb[f + 16384] = make_uint4(w2[0], w2[1], w2[2], w2[3]);
}

__global__ __launch_bounds__(NTHREADS, 8)
void router_kernel(const float* __restrict__ x,
                   const uint4* __restrict__ wsb,
                   float* __restrict__ out)
{
    __shared__ f32x4  part[4][4][64];   // [kq][tile][lane]  16 KiB
    __shared__ float4 cand[4][TPB];     // [egrp][token] raw (V1,E1,V2,E2)
    __shared__ float4 cand2[TPB];       // [token] (p1,p2,E1,E2)

    const int tid  = threadIdx.x;
    const int lane = tid & 63;
    const int wq   = tid >> 6;       // wave id = K-quarter; also tile owner
    const int tok0 = blockIdx.x * TPB;
    const int col  = lane & 15;      // token row (A) / expert col (C)
    const int grp  = lane >> 4;

    // A source: lane holds token (tok0+col), k-slice grp*8..+7 within each kk
    const float* xrow = x + (size_t)(tok0 + col) * HDIM + wq * 256 + grp * 8;

    f32x4 acc[4] = {{0,0,0,0}, {0,0,0,0}, {0,0,0,0}, {0,0,0,0}};

#pragma unroll 1
    for (int kk = 0; kk < NKKW; ++kk) {
        const float4 xa = *(const float4*)(xrow + kk * 32);
        const float4 xb = *(const float4*)(xrow + kk * 32 + 4);
        uint32_t w0[4], w1[4], w2[4];
        split8(xa, xb, w0, w1, w2);
        const short8 fa0 = frag_of(w0[0], w0[1], w0[2], w0[3]);
        const short8 fa1 = frag_of(w1[0], w1[1], w1[2], w1[3]);
        const short8 fa2 = frag_of(w2[0], w2[1], w2[2], w2[3]);

        const int fbase = (wq * NKKW + kk) * 256 + lane;
#pragma unroll
        for (int t = 0; t < 4; ++t) {
            const short8 fb0 = frag_of4(wsb[fbase + t * 64]);
            const short8 fb1 = frag_of4(wsb[8192 + fbase + t * 64]);
            const short8 fb2 = frag_of4(wsb[16384 + fbase + t * 64]);
            f32x4 a = acc[t];
            a = __builtin_amdgcn_mfma_f32_16x16x32_bf16(fa2, fb0, a, 0, 0, 0);
            a = __builtin_amdgcn_mfma_f32_16x16x32_bf16(fa0, fb2, a, 0, 0, 0);
            a = __builtin_amdgcn_mfma_f32_16x16x32_bf16(fa1, fb1, a, 0, 0, 0);
            a = __builtin_amdgcn_mfma_f32_16x16x32_bf16(fa1, fb0, a, 0, 0, 0);
            a = __builtin_amdgcn_mfma_f32_16x16x32_bf16(fa0, fb1, a, 0, 0, 0);
            a = __builtin_amdgcn_mfma_f32_16x16x32_bf16(fa0, fb0, a, 0, 0, 0);
            acc[t] = a;
        }
    }

    // ---- split-K reduce: wave wq owns tile wq (fixed order = deterministic)
#pragma unroll
    for (int t = 0; t < 4; ++t) part[wq][t][lane] = acc[t];
    __syncthreads();

    f32x4 fin = part[0][wq][lane];
#pragma unroll
    for (int q = 1; q < 4; ++q) fin += part[q][wq][lane];

    // ---- per-wave top-2 over this tile's 16 expert cols, per token reg ----
#define INS(v, e)                                                              \
    do {                                                                       \
        const float _v = (v); const int _e = (e);                              \
        if (_v > V1 || (_v == V1 && _e < E1)) {                                \
            V2 = V1; E2 = E1; V1 = _v; E1 = _e;                                \
        } else if (_v > V2 || (_v == V2 && _e < E2)) {                         \
            V2 = _v; E2 = _e;                                                  \
        }                                                                      \
    } while (0)

#pragma unroll
    for (int i = 0; i < 4; ++i) {
        float V1 = fin[i]; int E1 = wq * 16 + col;
        float V2 = -INFINITY; int E2 = NEXP;
#pragma unroll
        for (int m = 1; m <= 8; m <<= 1) {
            const float pv1 = __shfl_xor(V1, m, 64);
            const int   pe1 = __shfl_xor(E1, m, 64);
            const float pv2 = __shfl_xor(V2, m, 64);
            const int   pe2 = __shfl_xor(E2, m, 64);
            INS(pv1, pe1);
            INS(pv2, pe2);
        }
        if (col == 0) {
            float4 c;
            c.x = V1; c.y = __int_as_float(E1);
            c.z = V2; c.w = __int_as_float(E2);
            cand[wq][grp * 4 + i] = c;
        }
    }
    __syncthreads();

    // ---- merge 4 expert groups per token (ascending group, lowest-idx ties)
    if (tid < TPB) {
        float V1 = -INFINITY, V2 = -INFINITY; int E1 = 0, E2 = 0;
#pragma unroll
        for (int ww = 0; ww < 4; ++ww) {
            const float4 q = cand[ww][tid];
            const float a = q.x; const int ea = __float_as_int(q.y);
            const float b = q.z; const int eb = __float_as_int(q.w);
            if (a > V1)      { V2 = V1; E2 = E1; V1 = a; E1 = ea; }
            else if (a > V2) { V2 = a; E2 = ea; }
            if (b > V1)      { V2 = V1; E2 = E1; V1 = b; E1 = eb; }
            else if (b > V2) { V2 = b; E2 = eb; }
        }
        const float et = expf(V2 - V1);
        float4 c2;
        c2.x = 1.f / (1.f + et);
        c2.y = et / (1.f + et);
        c2.z = __int_as_float(E1);
        c2.w = __int_as_float(E2);
        cand2[tid] = c2;
    }
#undef INS
    __syncthreads();

    // ---- coalesced output: 16 tokens x 16 quads = 256 float4 ----
    {
        const int tt = tid >> 4, q = tid & 15;
        const float4 c = cand2[tt];
        const int E1 = __float_as_int(c.z), E2 = __float_as_int(c.w);
        float4 o;
        float* of = (float*)&o;
#pragma unroll
        for (int ii = 0; ii < 4; ++ii) {
            const int e = 4 * q + ii;
            of[ii] = (e == E1) ? c.x : (e == E2) ? c.y : 0.f;
        }
        *(float4*)(out + (size_t)(tok0 + tt) * NEXP + q * 4) = o;
    }
}

extern "C" void kernel_launch(void* const* d_in, const int* in_sizes, int n_in,
                              void* d_out, int out_size, void* d_ws, size_t ws_size,
                              hipStream_t stream)
{
    const float* x   = (const float*)d_in[0];
    const float* emb = (const float*)d_in[1];
    float* out = (float*)d_out;
    uint4* wsb = (uint4*)d_ws;                   // 384 KiB: 3 limb B-frag arrays

    prepack_kernel<<<32, 256, 0, stream>>>(emb, wsb);

    const int n_tokens = in_sizes[0] / HDIM;     // 32768
    const int nblocks  = n_tokens / TPB;         // 2048

    router_kernel<<<nblocks, NTHREADS, 0, stream>>>(x, wsb, out);
}